// Round 9
// baseline (711.977 us; speedup 1.0000x reference)
//
#include <hip/hip_runtime.h>

#define NN 50000
#define NE 800000
#define DD 128
#define PEW 98
#define KPE 226
#define WSLOT 32768   // bf16 elements per transposed-weight slot (128 x 256 max)
#define NB 49         // scan blocks per level: ceil(NN/1024)
#define GX 782        // ceil(NN/64) gemm row-tiles
#define HISTB 3125    // ceil(NE/256)
#define FILLB 3125
#define PREPXB 25000  // NN*256/512
#define PREPB 80
#define AGGB 12500    // ceil(NN/4)

typedef __attribute__((ext_vector_type(8))) short short8;
typedef __attribute__((ext_vector_type(4))) float float4v;

// Kept so anything that looks up the original kernel name still finds a symbol.
__global__ void GraphTrajSTEncoder_67362267070834_kernel() {}

// ---------------- dtype helpers ----------------

__device__ __forceinline__ float bfbits_to_f(unsigned int u16) {
    unsigned int v = u16 << 16;
    float f;
    __builtin_memcpy(&f, &v, 4);
    return f;
}

__device__ __forceinline__ float bits_to_f(unsigned int v) {
    float f;
    __builtin_memcpy(&f, &v, 4);
    return f;
}

__device__ __forceinline__ int f_as_i(float f) {
    int i;
    __builtin_memcpy(&i, &f, 4);
    return i;
}

__device__ __forceinline__ unsigned short f_to_bfbits(float f) {
    unsigned int b;
    __builtin_memcpy(&b, &f, 4);
    unsigned int r = b + 0x7FFFu + ((b >> 16) & 1u);   // round to nearest even
    return (unsigned short)(r >> 16);
}

__device__ __forceinline__ float ldf(const void* p, int i, int isbf) {
    if (isbf) return bfbits_to_f(((const unsigned short*)p)[i]);
    return ((const float*)p)[i];
}

// ---------------- dispatch 1: dtype detect + zero degree arrays ----------------
__global__ __launch_bounds__(256)
void k_detect0(const unsigned int* xw, int* flag, float* dout_sentinel,
               int* deg0, int* deg1) {
    if (blockIdx.x == 0) {
        __shared__ int cnt;
        if (threadIdx.x == 0) cnt = 0;
        __syncthreads();
        unsigned int w = xw[threadIdx.x];
        unsigned int e = (w >> 7) & 0xFFu;
        atomicAdd(&cnt, (e >= 100u && e <= 150u) ? 1 : 0);
        __syncthreads();
        if (threadIdx.x == 0) {
            flag[0] = (cnt >= 128) ? 1 : 0;
            dout_sentinel[0] = 1.0e6f;
        }
    } else {
        int i = (blockIdx.x - 1) * 256 + threadIdx.x;
        if (i < NN) deg0[i] = 0;
        else if (i < 2 * NN) deg1[i - NN] = 0;
    }
}

// ---------------- dispatch 2 (kA): hist + prepx + weight-prep fused ----------------
__global__ __launch_bounds__(256)
void kA(const int* __restrict__ ei0, const int* __restrict__ ei1,
        int* deg0, int* deg1,
        const void* x, const void* pe, unsigned short* __restrict__ xcat,
        const void* s0, const void* s1, const void* s2, const void* s3,
        const void* s4, const void* s5, const void* s6, const void* s7,
        const void* s8, const void* s9,
        unsigned short* __restrict__ wt, const int* __restrict__ dflag) {
    int b = blockIdx.x;
    int t = threadIdx.x;
    if (b < 2 * HISTB) {
        // degree histogram (real edges only; self loop handled analytically)
        int lvl = b >= HISTB;
        const int* col = (lvl ? ei1 : ei0) + NE;
        int* deg = lvl ? deg1 : deg0;
        int i = (b - (lvl ? HISTB : 0)) * 256 + t;
        if (i < NE) atomicAdd(&deg[col[i]], 1);
    } else if (b < 2 * HISTB + PREPXB) {
        // concat(x, pe) -> bf16 xcat[N,256], 2 elems/thread
        int isbf = dflag[0];
        int idx = (b - 2 * HISTB) * 512 + t * 2;
#pragma unroll
        for (int j = 0; j < 2; j++) {
            int id = idx + j;
            int row = id >> 8, c = id & 255;
            float v = 0.f;
            if (c < DD) v = ldf(x, row * DD + c, isbf);
            else if (c < KPE) v = ldf(pe, row * PEW + (c - DD), isbf);
            xcat[id] = f_to_bfbits(v);
        }
    } else {
        // weight transpose to bf16 [n][k]
        int b3 = b - 2 * HISTB - PREPXB;
        int y = b3 >> 3, bx = b3 & 7;
        const void* src =
            (y == 0) ? s0 : (y == 1) ? s1 : (y == 2) ? s2 : (y == 3) ? s3 :
            (y == 4) ? s4 : (y == 5) ? s5 : (y == 6) ? s6 : (y == 7) ? s7 :
            (y == 8) ? s8 : s9;
        int KP = (y < 2) ? 256 : 128;
        int Ksrc = (y < 2) ? KPE : DD;
        int kt = bx >> 1, nt = bx & 1;
        if (kt * 64 >= KP) return;
        __shared__ float tile[64][65];
        int cc = t & 63, rr = t >> 6;
        int k0 = kt * 64, n0 = nt * 64;
        int isbf = dflag[0];
#pragma unroll
        for (int i = 0; i < 16; i++) {
            int k = k0 + rr + i * 4;
            tile[rr + i * 4][cc] = (k < Ksrc) ? ldf(src, k * DD + n0 + cc, isbf) : 0.f;
        }
        __syncthreads();
        unsigned short* w = wt + y * WSLOT;
#pragma unroll
        for (int i = 0; i < 16; i++) {
            int nn = rr + i * 4;
            w[(n0 + nn) * KP + k0 + cc] = f_to_bfbits(tile[cc][nn]);
        }
    }
}

// ---------------- parallel scan (deg_raw; dis = rsqrt(deg+1)) ----------------
__global__ void k_scan1(const int* __restrict__ deg0, const int* __restrict__ deg1,
                        float* __restrict__ dis0, float* __restrict__ dis1,
                        int* __restrict__ bsum, int n) {
    int l = blockIdx.y;
    const int* deg = l ? deg1 : deg0;
    float* dis = l ? dis1 : dis0;
    int t = threadIdx.x;
    int base = blockIdx.x * 1024 + t * 4;
    int d[4] = {0, 0, 0, 0};
    if (base + 3 < n) {
        int4 q = *(const int4*)(deg + base);
        d[0] = q.x; d[1] = q.y; d[2] = q.z; d[3] = q.w;
    } else {
#pragma unroll
        for (int j = 0; j < 4; j++) if (base + j < n) d[j] = deg[base + j];
    }
#pragma unroll
    for (int j = 0; j < 4; j++)
        if (base + j < n) dis[base + j] = rsqrtf((float)(d[j] + 1));
    int s = d[0] + d[1] + d[2] + d[3];
#pragma unroll
    for (int off = 32; off >= 1; off >>= 1) s += __shfl_down(s, off, 64);
    __shared__ int ws[4];
    if ((t & 63) == 0) ws[t >> 6] = s;
    __syncthreads();
    if (t == 0) bsum[l * 64 + blockIdx.x] = ws[0] + ws[1] + ws[2] + ws[3];
}

__global__ void k_scan2(const int* __restrict__ bsum, int* __restrict__ boff) {
    int lane = threadIdx.x & 63;
    int l = threadIdx.x >> 6;
    int v = (lane < NB) ? bsum[l * 64 + lane] : 0;
    int s = v;
#pragma unroll
    for (int off = 1; off < 64; off <<= 1) {
        int u = __shfl_up(s, off, 64);
        if (lane >= off) s += u;
    }
    boff[l * 64 + lane] = s - v;   // exclusive
}

__global__ void k_scan3(const int* __restrict__ deg0, const int* __restrict__ deg1,
                        const int* __restrict__ boff,
                        int* __restrict__ cur0, int* __restrict__ cur1, int n) {
    int l = blockIdx.y;
    const int* deg = l ? deg1 : deg0;
    int* cur = l ? cur1 : cur0;
    int t = threadIdx.x;
    int base = blockIdx.x * 1024 + t * 4;
    int d[4] = {0, 0, 0, 0};
    if (base + 3 < n) {
        int4 q = *(const int4*)(deg + base);
        d[0] = q.x; d[1] = q.y; d[2] = q.z; d[3] = q.w;
    } else {
#pragma unroll
        for (int j = 0; j < 4; j++) if (base + j < n) d[j] = deg[base + j];
    }
    int s = d[0] + d[1] + d[2] + d[3];
    __shared__ int sc[256];
    sc[t] = s;
    __syncthreads();
    for (int off = 1; off < 256; off <<= 1) {
        int v = (t >= off) ? sc[t - off] : 0;
        __syncthreads();
        sc[t] += v;
        __syncthreads();
    }
    int p = boff[l * 64 + blockIdx.x] + sc[t] - s;   // exclusive prefix
#pragma unroll
    for (int j = 0; j < 4; j++) {
        if (base + j < n) { cur[base + j] = p; p += d[j]; }
    }
}

// ---------------- shared GEMM tile body (64x128 tile, bf16 MFMA) ----------------
__device__ __forceinline__ void gemm_tile(const unsigned short* __restrict__ A,
                                          const unsigned short* __restrict__ wt,
                                          unsigned short* __restrict__ out,
                                          int M, int KP, int row0) {
    __shared__ short A_s[64 * 72];
    __shared__ short B_s[128 * 72];
    int tid = threadIdx.x;
    int lane = tid & 63, w = tid >> 6;
    int m = lane & 15, quad = lane >> 4;
    float4v acc[8];
#pragma unroll
    for (int t = 0; t < 8; t++) acc[t] = (float4v){0.f, 0.f, 0.f, 0.f};
    int nch = KP >> 6;
    for (int c = 0; c < nch; c++) {
#pragma unroll
        for (int i = 0; i < 2; i++) {
            int e = (i * 256 + tid) * 8;
            int r = e >> 6, cc = e & 63;
            int rr = row0 + r;
            short8 v = {0, 0, 0, 0, 0, 0, 0, 0};
            if (rr < M) v = *(const short8*)(A + rr * KP + c * 64 + cc);
            *(short8*)&A_s[r * 72 + cc] = v;
        }
#pragma unroll
        for (int i = 0; i < 4; i++) {
            int e = (i * 256 + tid) * 8;
            int nr = e >> 6, kk = e & 63;
            *(short8*)&B_s[nr * 72 + kk] = *(const short8*)(wt + nr * KP + c * 64 + kk);
        }
        __syncthreads();
#pragma unroll
        for (int c2 = 0; c2 < 2; c2++) {
            short8 a = *(short8*)&A_s[(w * 16 + m) * 72 + c2 * 32 + quad * 8];
#pragma unroll
            for (int t = 0; t < 8; t++) {
                short8 b = *(short8*)&B_s[(t * 16 + m) * 72 + c2 * 32 + quad * 8];
                acc[t] = __builtin_amdgcn_mfma_f32_16x16x32_bf16(a, b, acc[t], 0, 0, 0);
            }
        }
        __syncthreads();
    }
#pragma unroll
    for (int t = 0; t < 8; t++) {
#pragma unroll
        for (int r = 0; r < 4; r++) {
            int row = row0 + w * 16 + quad * 4 + r;
            if (row < M) out[row * DD + t * 16 + m] = f_to_bfbits(acc[t][r]);
        }
    }
}

// ---------------- dispatch 6 (kB): edge fill + PE GEMM fused ----------------
__global__ __launch_bounds__(256)
void kB(const int* __restrict__ ei0, const void* __restrict__ ea0,
        const float* __restrict__ dis0, int* cur0, int4* __restrict__ edges0,
        const int* __restrict__ ei1, const void* __restrict__ ea1,
        const float* __restrict__ dis1, int* cur1, int4* __restrict__ edges1,
        const unsigned short* __restrict__ xcat, const unsigned short* __restrict__ wt,
        unsigned short* __restrict__ xpe1, unsigned short* __restrict__ xpe2,
        const int* __restrict__ dflag) {
    int b = blockIdx.x;
    if (b < 2 * FILLB) {
        int lvl = b >= FILLB;
        const int* row = lvl ? ei1 : ei0;
        const int* col = row + NE;
        const void* attr = lvl ? ea1 : ea0;
        const float* dis = lvl ? dis1 : dis0;
        int* cur = lvl ? cur1 : cur0;
        int4* edges = lvl ? edges1 : edges0;
        int i = (b - (lvl ? FILLB : 0)) * 256 + threadIdx.x;
        if (i < NE) {
            int c = col[i], r = row[i];
            int p = atomicAdd(&cur[c], 1);
            float a = ldf(attr, i, dflag[0]);
            float w2 = (a > 0.f) ? fminf(rsqrtf(a), 1.f) : 0.f;
            int4 rec;
            rec.x = r;
            rec.y = f_as_i(dis[r] * dis[c]);
            rec.z = f_as_i(w2);
            rec.w = 0;
            edges[p] = rec;
        }
    } else {
        int b2 = b - 2 * FILLB;
        int mat = b2 >= GX;
        int bx = mat ? b2 - GX : b2;
        gemm_tile(xcat, wt + (mat ? WSLOT : 0), mat ? xpe2 : xpe1, NN, 256, bx * 64);
    }
}

// ---------------- layer GEMM (plain): h{1,2} = A @ W{1,2} ----------------
__global__ __launch_bounds__(256)
void k_gemm2(const unsigned short* __restrict__ A,
             const unsigned short* __restrict__ wt1,
             const unsigned short* __restrict__ wt2,
             unsigned short* __restrict__ h1, unsigned short* __restrict__ h2) {
    gemm_tile(A, blockIdx.y ? wt2 : wt1, blockIdx.y ? h2 : h1, NN, 128,
              blockIdx.x * 64);
}

// ---------------- aggregation body (unroll-8, 16B records, analytic self-loop) ----
#define EDGE(j) \
    int4 e##j = edges[s + j]; \
    unsigned int p1##j = *(const unsigned int*)(h1 + e##j.x * DD + c0); \
    unsigned int p2##j = *(const unsigned int*)(h2 + e##j.x * DD + c0);
#define ACC2(j, AX, AY) { \
    float w1_ = bits_to_f((unsigned int)e##j.y); \
    float w2_ = bits_to_f((unsigned int)e##j.z); \
    AX = fmaf(w1_, bits_to_f(p1##j << 16), AX); \
    AX = fmaf(w2_, bits_to_f(p2##j << 16), AX); \
    AY = fmaf(w1_, bits_to_f(p1##j & 0xFFFF0000u), AY); \
    AY = fmaf(w2_, bits_to_f(p2##j & 0xFFFF0000u), AY); }

__device__ __forceinline__ void agg_body(int wave, int lane,
        const int4* __restrict__ edges, const int* __restrict__ cur,
        const int* __restrict__ deg, const float* __restrict__ dis,
        const unsigned short* __restrict__ h1, const unsigned short* __restrict__ h2,
        const unsigned short* __restrict__ blendIn,
        unsigned short* __restrict__ outBf, void* __restrict__ outFinal,
        const int* __restrict__ dflag, int mode) {
    int end = cur[wave];
    int start = end - deg[wave];
    float dn = dis[wave];
    int c0 = lane * 2;
    float ax0 = 0.f, ay0 = 0.f, ax1 = 0.f, ay1 = 0.f;
    float ax2 = 0.f, ay2 = 0.f, ax3 = 0.f, ay3 = 0.f;
    int s = start;
    for (; s + 8 <= end; s += 8) {
        EDGE(0) EDGE(1) EDGE(2) EDGE(3) EDGE(4) EDGE(5) EDGE(6) EDGE(7)
        ACC2(0, ax0, ay0); ACC2(1, ax1, ay1); ACC2(2, ax2, ay2); ACC2(3, ax3, ay3);
        ACC2(4, ax0, ay0); ACC2(5, ax1, ay1); ACC2(6, ax2, ay2); ACC2(7, ax3, ay3);
    }
    for (; s < end; s++) {
        EDGE(0)
        ACC2(0, ax0, ay0);
    }
    // self loop: w1 = dis^2, w2 = 1
    {
        unsigned int q1 = *(const unsigned int*)(h1 + wave * DD + c0);
        unsigned int q2 = *(const unsigned int*)(h2 + wave * DD + c0);
        float dn2 = dn * dn;
        ax0 = fmaf(dn2, bits_to_f(q1 << 16), ax0) + bits_to_f(q2 << 16);
        ay0 = fmaf(dn2, bits_to_f(q1 & 0xFFFF0000u), ay0) + bits_to_f(q2 & 0xFFFF0000u);
    }
    float rx = fmaxf((ax0 + ax1) + (ax2 + ax3), 0.f);
    float ry = fmaxf((ay0 + ay1) + (ay2 + ay3), 0.f);
    if (mode >= 1) {
        unsigned int pc = *(const unsigned int*)(blendIn + wave * DD + c0);
        rx = 0.5f * rx + 0.5f * bits_to_f(pc << 16);
        ry = 0.5f * ry + 0.5f * bits_to_f(pc & 0xFFFF0000u);
    }
    if (mode == 2) {
        if (dflag[0]) {
            unsigned int pk = (unsigned int)f_to_bfbits(rx) |
                              ((unsigned int)f_to_bfbits(ry) << 16);
            *(unsigned int*)((unsigned short*)outFinal + wave * DD + c0) = pk;
        } else {
            float* of = (float*)outFinal;
            of[wave * DD + c0]     = rx;
            of[wave * DD + c0 + 1] = ry;
        }
    } else {
        unsigned int pk = (unsigned int)f_to_bfbits(rx) |
                          ((unsigned int)f_to_bfbits(ry) << 16);
        *(unsigned int*)(outBf + wave * DD + c0) = pk;
    }
}

// ---------------- plain aggregation dispatch ----------------
__global__ __launch_bounds__(256)
void k_agg(const int4* __restrict__ edges, const int* __restrict__ cur,
           const int* __restrict__ deg, const float* __restrict__ dis,
           const unsigned short* __restrict__ h1, const unsigned short* __restrict__ h2,
           const unsigned short* __restrict__ blendIn,
           unsigned short* __restrict__ outBf, void* __restrict__ outFinal,
           const int* __restrict__ dflag, int mode) {
    int wave = (blockIdx.x * blockDim.x + threadIdx.x) >> 6;
    int lane = threadIdx.x & 63;
    if (wave >= NN) return;
    agg_body(wave, lane, edges, cur, deg, dis, h1, h2, blendIn, outBf, outFinal,
             dflag, mode);
}

// ---------------- dispatch 8/11 (kC): agg(mode0) + next-layer GEMM fused ----------
__global__ __launch_bounds__(256)
void kC(const int4* __restrict__ edges, const int* __restrict__ cur,
        const int* __restrict__ deg, const float* __restrict__ dis,
        const unsigned short* __restrict__ h1g, const unsigned short* __restrict__ h2g,
        unsigned short* __restrict__ outBf,
        const unsigned short* __restrict__ Ag,
        const unsigned short* __restrict__ wt1, const unsigned short* __restrict__ wt2,
        unsigned short* __restrict__ h1o, unsigned short* __restrict__ h2o) {
    int b = blockIdx.x;
    if (b < AGGB) {
        int wave = (b * 256 + threadIdx.x) >> 6;
        int lane = threadIdx.x & 63;
        if (wave < NN)
            agg_body(wave, lane, edges, cur, deg, dis, h1g, h2g,
                     (const unsigned short*)0, outBf, (void*)0,
                     (const int*)0, 0);
    } else {
        int b2 = b - AGGB;
        int mat = b2 >= GX;
        int bx = mat ? b2 - GX : b2;
        gemm_tile(Ag, mat ? wt2 : wt1, mat ? h2o : h1o, NN, 128, bx * 64);
    }
}

// ---------------- Launch ----------------

#define PADUP(x) (((x) + 255) & ~(size_t)255)

extern "C" void kernel_launch(void* const* d_in, const int* in_sizes, int n_in,
                              void* d_out, int out_size, void* d_ws, size_t ws_size,
                              hipStream_t stream) {
    (void)in_sizes; (void)n_in; (void)out_size; (void)ws_size;

    const void* x    = d_in[0];
    const void* d2an = d_in[1];
    const int*  ei0  = (const int*)d_in[2];
    const void* ea0  = d_in[3];
    const int*  ei1  = (const int*)d_in[4];
    const void* ea1  = d_in[5];

    char* p = (char*)d_ws;
    unsigned short* xpe1 = (unsigned short*)p; p += PADUP((size_t)NN * DD * 2); // -> xm
    unsigned short* xpe2 = (unsigned short*)p; p += PADUP((size_t)NN * DD * 2);
    unsigned short* x0b  = (unsigned short*)p; p += PADUP((size_t)NN * DD * 2);
    unsigned short* xcat = (unsigned short*)p; p += PADUP((size_t)NN * 256 * 2);
    unsigned short* h1a  = xcat;               // xcat dead after kB
    unsigned short* h2a  = xcat + (size_t)NN * DD;
    unsigned short* h1b  = (unsigned short*)p; p += PADUP((size_t)NN * DD * 2);
    unsigned short* h2b  = (unsigned short*)p; p += PADUP((size_t)NN * DD * 2);
    unsigned short* wt   = (unsigned short*)p; p += PADUP((size_t)10 * WSLOT * 2);
    int*   deg0 = (int*)p;    p += PADUP((size_t)NN * 4);
    int*   cur0 = (int*)p;    p += PADUP((size_t)NN * 4);
    float* dis0 = (float*)p;  p += PADUP((size_t)NN * 4);
    int*   deg1 = (int*)p;    p += PADUP((size_t)NN * 4);
    int*   cur1 = (int*)p;    p += PADUP((size_t)NN * 4);
    float* dis1 = (float*)p;  p += PADUP((size_t)NN * 4);
    int4*  edges0 = (int4*)p; p += PADUP((size_t)NE * 16);
    int4*  edges1 = (int4*)p; p += PADUP((size_t)NE * 16);
    int*   bsum = (int*)p;    p += PADUP((size_t)128 * 4);
    int*   boff = (int*)p;    p += PADUP((size_t)128 * 4);
    int*   dflag = (int*)p;

    // 1. detect + zero degrees
    k_detect0<<<392, 256, 0, stream>>>((const unsigned int*)x, dflag, (float*)d_out,
                                       deg0, deg1);
    // 2. hist + prepx + weight prep (fused)
    kA<<<2 * HISTB + PREPXB + PREPB, 256, 0, stream>>>(
        ei0, ei1, deg0, deg1, x, d2an, xcat,
        d_in[6], d_in[7], d_in[8], d_in[9], d_in[10], d_in[11], d_in[12],
        d_in[13], d_in[14], d_in[15], wt, dflag);
    // 3-5. parallel scan
    k_scan1<<<dim3(NB, 2), 256, 0, stream>>>(deg0, deg1, dis0, dis1, bsum, NN);
    k_scan2<<<1, 128, 0, stream>>>(bsum, boff);
    k_scan3<<<dim3(NB, 2), 256, 0, stream>>>(deg0, deg1, boff, cur0, cur1, NN);
    // 6. fill + PE GEMM (fused)
    kB<<<2 * FILLB + 2 * GX, 256, 0, stream>>>(
        ei0, ea0, dis0, cur0, edges0,
        ei1, ea1, dis1, cur1, edges1,
        xcat, wt, xpe1, xpe2, dflag);
    // 7. gemm2 L1 -> h_a
    k_gemm2<<<dim3(GX, 2), 256, 0, stream>>>(xpe1, wt + 2 * WSLOT, wt + 3 * WSLOT,
                                             h1a, h2a);
    // 8. agg L1 (h_a -> x0b) + gemm2 L2 (xpe2 -> h_b)   [fused]
    kC<<<AGGB + 2 * GX, 256, 0, stream>>>(edges0, cur0, deg0, dis0, h1a, h2a, x0b,
                                          xpe2, wt + 4 * WSLOT, wt + 5 * WSLOT,
                                          h1b, h2b);
    // 9. agg L2: xm = 0.5*relu(agg(h_b)) + 0.5*x0b  -> xpe1
    k_agg<<<AGGB, 256, 0, stream>>>(edges1, cur1, deg1, dis1, h1b, h2b,
                                    x0b, xpe1, (void*)0, dflag, 1);
    // 10. gemm2 L3 (xm -> h_a)
    k_gemm2<<<dim3(GX, 2), 256, 0, stream>>>(xpe1, wt + 6 * WSLOT, wt + 7 * WSLOT,
                                             h1a, h2a);
    // 11. agg L3 (h_a -> x0b) + gemm2 L4 (xm -> h_b)   [fused]
    kC<<<AGGB + 2 * GX, 256, 0, stream>>>(edges0, cur0, deg0, dis0, h1a, h2a, x0b,
                                          xpe1, wt + 8 * WSLOT, wt + 9 * WSLOT,
                                          h1b, h2b);
    // 12. agg L4: out = 0.5*relu(agg(h_b)) + 0.5*x0b  (bf16/f32 per dflag)
    k_agg<<<AGGB, 256, 0, stream>>>(edges1, cur1, deg1, dis1, h1b, h2b,
                                    x0b, (unsigned short*)0, d_out, dflag, 2);
}

// Round 10
// 583.101 us; speedup vs baseline: 1.2210x; 1.2210x over previous
//
#include <hip/hip_runtime.h>

#define NN 50000
#define NE 800000
#define DD 128
#define PEW 98
#define KPE 226
#define WSLOT 32768   // bf16 elements per weight slot (128 n x 256 k)
#define NB 49         // scan blocks per level: ceil(NN/1024)
#define GX 782        // ceil(NN/64) gemm row-tiles
#define HISTB 3125    // ceil(NE/256)
#define FILLB 3125
#define PREPXB 25000  // NN*256/512
#define PREPB 48      // 6 slots x 8 tile-blocks
#define AGGB 12500    // ceil(NN/4)

typedef __attribute__((ext_vector_type(8))) short short8;
typedef __attribute__((ext_vector_type(4))) float float4v;

// Kept so anything that looks up the original kernel name still finds a symbol.
__global__ void GraphTrajSTEncoder_67362267070834_kernel() {}

// ---------------- dtype helpers ----------------

__device__ __forceinline__ float bfbits_to_f(unsigned int u16) {
    unsigned int v = u16 << 16;
    float f;
    __builtin_memcpy(&f, &v, 4);
    return f;
}

__device__ __forceinline__ float bits_to_f(unsigned int v) {
    float f;
    __builtin_memcpy(&f, &v, 4);
    return f;
}

__device__ __forceinline__ int f_as_i(float f) {
    int i;
    __builtin_memcpy(&i, &f, 4);
    return i;
}

__device__ __forceinline__ unsigned short f_to_bfbits(float f) {
    unsigned int b;
    __builtin_memcpy(&b, &f, 4);
    unsigned int r = b + 0x7FFFu + ((b >> 16) & 1u);   // round to nearest even
    return (unsigned short)(r >> 16);
}

__device__ __forceinline__ float ldf(const void* p, int i, int isbf) {
    if (isbf) return bfbits_to_f(((const unsigned short*)p)[i]);
    return ((const float*)p)[i];
}

// ---------------- dispatch 1: dtype detect + zero degree arrays ----------------
__global__ __launch_bounds__(256)
void k_detect0(const unsigned int* xw, int* flag, float* dout_sentinel,
               int* deg0, int* deg1) {
    if (blockIdx.x == 0) {
        __shared__ int cnt;
        if (threadIdx.x == 0) cnt = 0;
        __syncthreads();
        unsigned int w = xw[threadIdx.x];
        unsigned int e = (w >> 7) & 0xFFu;
        atomicAdd(&cnt, (e >= 100u && e <= 150u) ? 1 : 0);
        __syncthreads();
        if (threadIdx.x == 0) {
            flag[0] = (cnt >= 128) ? 1 : 0;
            dout_sentinel[0] = 1.0e6f;
        }
    } else {
        int i = (blockIdx.x - 1) * 256 + threadIdx.x;
        if (i < NN) deg0[i] = 0;
        else if (i < 2 * NN) deg1[i - NN] = 0;
    }
}

// ---------------- dispatch 2 (kA): hist + prepx + weight-prep (K=256 slots) -------
// slot y (0..5), Wt[n*256 + k]:
//   y<2 : nodeLin y   -> src[k*128+n], k<226, else 0
//   y>=2: layer y-2   -> k<128: lin1[k*128+n]; k>=128: lin2[(k-128)*128+n]
__global__ __launch_bounds__(256)
void kA(const int* __restrict__ ei0, const int* __restrict__ ei1,
        int* deg0, int* deg1,
        const void* x, const void* pe, unsigned short* __restrict__ xcat,
        const void* n1, const void* n2,
        const void* l11, const void* l21, const void* l12, const void* l22,
        const void* l13, const void* l23, const void* l14, const void* l24,
        unsigned short* __restrict__ wt, const int* __restrict__ dflag) {
    int b = blockIdx.x;
    int t = threadIdx.x;
    if (b < 2 * HISTB) {
        int lvl = b >= HISTB;
        const int* col = (lvl ? ei1 : ei0) + NE;
        int* deg = lvl ? deg1 : deg0;
        int i = (b - (lvl ? HISTB : 0)) * 256 + t;
        if (i < NE) atomicAdd(&deg[col[i]], 1);
    } else if (b < 2 * HISTB + PREPXB) {
        int isbf = dflag[0];
        int idx = (b - 2 * HISTB) * 512 + t * 2;
#pragma unroll
        for (int j = 0; j < 2; j++) {
            int id = idx + j;
            int row = id >> 8, c = id & 255;
            float v = 0.f;
            if (c < DD) v = ldf(x, row * DD + c, isbf);
            else if (c < KPE) v = ldf(pe, row * PEW + (c - DD), isbf);
            xcat[id] = f_to_bfbits(v);
        }
    } else {
        int b3 = b - 2 * HISTB - PREPXB;
        int y = b3 >> 3, bx = b3 & 7;
        int kt = bx >> 1, nt = bx & 1;
        __shared__ float tile[64][65];
        int cc = t & 63, rr = t >> 6;
        int k0 = kt * 64, n0 = nt * 64;
        int isbf = dflag[0];
        const void* sA;   // source for k<128
        const void* sB;   // source for k>=128
        if (y == 0)      { sA = n1;  sB = n1; }
        else if (y == 1) { sA = n2;  sB = n2; }
        else if (y == 2) { sA = l11; sB = l21; }
        else if (y == 3) { sA = l12; sB = l22; }
        else if (y == 4) { sA = l13; sB = l23; }
        else             { sA = l14; sB = l24; }
#pragma unroll
        for (int i = 0; i < 16; i++) {
            int k = k0 + rr + i * 4;
            float v = 0.f;
            if (y < 2) {
                if (k < KPE) v = ldf(sA, k * DD + n0 + cc, isbf);
            } else {
                v = (k < 128) ? ldf(sA, k * DD + n0 + cc, isbf)
                              : ldf(sB, (k - 128) * DD + n0 + cc, isbf);
            }
            tile[rr + i * 4][cc] = v;
        }
        __syncthreads();
        unsigned short* w = wt + y * WSLOT;
#pragma unroll
        for (int i = 0; i < 16; i++) {
            int nn = rr + i * 4;
            w[(n0 + nn) * 256 + k0 + cc] = f_to_bfbits(tile[cc][nn]);
        }
    }
}

// ---------------- parallel scan (deg = real edges; dis = rsqrt(deg+1)) -----------
__global__ void k_scan1(const int* __restrict__ deg0, const int* __restrict__ deg1,
                        float* __restrict__ dis0, float* __restrict__ dis1,
                        int* __restrict__ bsum, int n) {
    int l = blockIdx.y;
    const int* deg = l ? deg1 : deg0;
    float* dis = l ? dis1 : dis0;
    int t = threadIdx.x;
    int base = blockIdx.x * 1024 + t * 4;
    int d[4] = {0, 0, 0, 0};
    if (base + 3 < n) {
        int4 q = *(const int4*)(deg + base);
        d[0] = q.x; d[1] = q.y; d[2] = q.z; d[3] = q.w;
    } else {
#pragma unroll
        for (int j = 0; j < 4; j++) if (base + j < n) d[j] = deg[base + j];
    }
#pragma unroll
    for (int j = 0; j < 4; j++)
        if (base + j < n) dis[base + j] = rsqrtf((float)(d[j] + 1));
    int s = d[0] + d[1] + d[2] + d[3];
#pragma unroll
    for (int off = 32; off >= 1; off >>= 1) s += __shfl_down(s, off, 64);
    __shared__ int ws[4];
    if ((t & 63) == 0) ws[t >> 6] = s;
    __syncthreads();
    if (t == 0) bsum[l * 64 + blockIdx.x] = ws[0] + ws[1] + ws[2] + ws[3];
}

__global__ void k_scan2(const int* __restrict__ bsum, int* __restrict__ boff) {
    int lane = threadIdx.x & 63;
    int l = threadIdx.x >> 6;
    int v = (lane < NB) ? bsum[l * 64 + lane] : 0;
    int s = v;
#pragma unroll
    for (int off = 1; off < 64; off <<= 1) {
        int u = __shfl_up(s, off, 64);
        if (lane >= off) s += u;
    }
    boff[l * 64 + lane] = s - v;   // exclusive
}

__global__ void k_scan3(const int* __restrict__ deg0, const int* __restrict__ deg1,
                        const int* __restrict__ boff,
                        int* __restrict__ cur0, int* __restrict__ cur1, int n) {
    int l = blockIdx.y;
    const int* deg = l ? deg1 : deg0;
    int* cur = l ? cur1 : cur0;
    int t = threadIdx.x;
    int base = blockIdx.x * 1024 + t * 4;
    int d[4] = {0, 0, 0, 0};
    if (base + 3 < n) {
        int4 q = *(const int4*)(deg + base);
        d[0] = q.x; d[1] = q.y; d[2] = q.z; d[3] = q.w;
    } else {
#pragma unroll
        for (int j = 0; j < 4; j++) if (base + j < n) d[j] = deg[base + j];
    }
    int s = d[0] + d[1] + d[2] + d[3];
    __shared__ int sc[256];
    sc[t] = s;
    __syncthreads();
    for (int off = 1; off < 256; off <<= 1) {
        int v = (t >= off) ? sc[t - off] : 0;
        __syncthreads();
        sc[t] += v;
        __syncthreads();
    }
    int p = boff[l * 64 + blockIdx.x] + sc[t] - s;   // exclusive prefix
#pragma unroll
    for (int j = 0; j < 4; j++) {
        if (base + j < n) { cur[base + j] = p; p += d[j]; }
    }
}

// ---- fill: 16B records {src, w1, w2, 0}, real edges only, levels via grid.y ----
__global__ void k_fill(const int* __restrict__ ei0, const void* __restrict__ ea0,
                       const float* __restrict__ dis0, int* cur0,
                       int4* __restrict__ edges0,
                       const int* __restrict__ ei1, const void* __restrict__ ea1,
                       const float* __restrict__ dis1, int* cur1,
                       int4* __restrict__ edges1,
                       const int* __restrict__ dflag) {
    int lvl = blockIdx.y;
    const int* row = lvl ? ei1 : ei0;
    const int* col = row + NE;
    const void* attr = lvl ? ea1 : ea0;
    const float* dis = lvl ? dis1 : dis0;
    int* cur = lvl ? cur1 : cur0;
    int4* edges = lvl ? edges1 : edges0;
    int i = blockIdx.x * 256 + threadIdx.x;
    if (i < NE) {
        int c = col[i], r = row[i];
        int p = atomicAdd(&cur[c], 1);
        float a = ldf(attr, i, dflag[0]);
        float w2 = (a > 0.f) ? fminf(rsqrtf(a), 1.f) : 0.f;
        int4 rec;
        rec.x = r;
        rec.y = f_as_i(dis[r] * dis[c]);
        rec.z = f_as_i(w2);
        rec.w = 0;
        edges[p] = rec;
    }
}

// ---------------- GEMM core: 64x128 tile, K=256, bf16 MFMA ----------------
__device__ __forceinline__ void gemm_core(const unsigned short* __restrict__ A,
                                          const unsigned short* __restrict__ wt,
                                          int row0, float4v acc[8]) {
    __shared__ short A_s[64 * 72];
    __shared__ short B_s[128 * 72];
    int tid = threadIdx.x;
    int lane = tid & 63, w = tid >> 6;
    int m = lane & 15, quad = lane >> 4;
#pragma unroll
    for (int t = 0; t < 8; t++) acc[t] = (float4v){0.f, 0.f, 0.f, 0.f};
    for (int c = 0; c < 4; c++) {
#pragma unroll
        for (int i = 0; i < 2; i++) {
            int e = (i * 256 + tid) * 8;
            int r = e >> 6, cc = e & 63;
            int rr = row0 + r;
            short8 v = {0, 0, 0, 0, 0, 0, 0, 0};
            if (rr < NN) v = *(const short8*)(A + rr * 256 + c * 64 + cc);
            *(short8*)&A_s[r * 72 + cc] = v;
        }
#pragma unroll
        for (int i = 0; i < 4; i++) {
            int e = (i * 256 + tid) * 8;
            int nr = e >> 6, kk = e & 63;
            *(short8*)&B_s[nr * 72 + kk] = *(const short8*)(wt + nr * 256 + c * 64 + kk);
        }
        __syncthreads();
#pragma unroll
        for (int c2 = 0; c2 < 2; c2++) {
            short8 a = *(short8*)&A_s[(w * 16 + m) * 72 + c2 * 32 + quad * 8];
#pragma unroll
            for (int t = 0; t < 8; t++) {
                short8 b = *(short8*)&B_s[(t * 16 + m) * 72 + c2 * 32 + quad * 8];
                acc[t] = __builtin_amdgcn_mfma_f32_16x16x32_bf16(a, b, acc[t], 0, 0, 0);
            }
        }
        __syncthreads();
    }
}

// ---------------- PE GEMM: xpe{1,2} = xcat @ nodeLin{1,2} (plain write) ----------
__global__ __launch_bounds__(256)
void k_gemm_pe(const unsigned short* __restrict__ xcat,
               const unsigned short* __restrict__ wt,
               unsigned short* __restrict__ out0, unsigned short* __restrict__ out1) {
    float4v acc[8];
    gemm_core(xcat, wt + (blockIdx.y ? WSLOT : 0), blockIdx.x * 64, acc);
    unsigned short* out = blockIdx.y ? out1 : out0;
    int lane = threadIdx.x & 63, w = threadIdx.x >> 6;
    int m = lane & 15, quad = lane >> 4;
    int row0 = blockIdx.x * 64;
#pragma unroll
    for (int t = 0; t < 8; t++)
#pragma unroll
        for (int r = 0; r < 4; r++) {
            int row = row0 + w * 16 + quad * 4 + r;
            if (row < NN) out[row * DD + t * 16 + m] = f_to_bfbits(acc[t][r]);
        }
}

// ---------------- layer GEMM: out = epilogue(acat @ Wcat) ----------------
// mode 1: relu -> bf16 out
// mode 2: 0.5*relu + 0.5*blend -> bf16 out
// mode 3: 0.5*relu + 0.5*blend -> outFinal (bf16 or f32 per dflag)
__global__ __launch_bounds__(256)
void k_gemmL(const unsigned short* __restrict__ acat,
             const unsigned short* __restrict__ wt,
             const unsigned short* __restrict__ blendIn,
             unsigned short* __restrict__ out, void* __restrict__ outFinal,
             const int* __restrict__ dflag, int mode) {
    float4v acc[8];
    gemm_core(acat, wt, blockIdx.x * 64, acc);
    int lane = threadIdx.x & 63, w = threadIdx.x >> 6;
    int m = lane & 15, quad = lane >> 4;
    int row0 = blockIdx.x * 64;
    int isbf = (mode == 3) ? dflag[0] : 1;
#pragma unroll
    for (int t = 0; t < 8; t++) {
        int colc = t * 16 + m;
#pragma unroll
        for (int r = 0; r < 4; r++) {
            int row = row0 + w * 16 + quad * 4 + r;
            if (row >= NN) continue;
            float v = fmaxf(acc[t][r], 0.f);
            if (mode >= 2)
                v = 0.5f * v + 0.5f * bfbits_to_f(blendIn[row * DD + colc]);
            if (mode == 3 && !isbf)
                ((float*)outFinal)[row * DD + colc] = v;
            else if (mode == 3)
                ((unsigned short*)outFinal)[row * DD + colc] = f_to_bfbits(v);
            else
                out[row * DD + colc] = f_to_bfbits(v);
        }
    }
}

// ---------------- dual-level aggregation over X (a1|a2 -> acat[N,256]) ----------
// one wave per node, lane = 2 cols; unroll-8, 2-way split accumulators;
// analytic self-loop (w1 = dis^2, w2 = 1).
#define AEDGE(j) \
    int4 e##j = edges[s + j]; \
    unsigned int p##j = *(const unsigned int*)(X + e##j.x * DD + c0);
#define AACC(j, A1L, A1H, A2L, A2H) { \
    float w1_ = bits_to_f((unsigned int)e##j.y); \
    float w2_ = bits_to_f((unsigned int)e##j.z); \
    float xl_ = bits_to_f(p##j << 16); \
    float xh_ = bits_to_f(p##j & 0xFFFF0000u); \
    A1L = fmaf(w1_, xl_, A1L); A1H = fmaf(w1_, xh_, A1H); \
    A2L = fmaf(w2_, xl_, A2L); A2H = fmaf(w2_, xh_, A2H); }

__global__ __launch_bounds__(256)
void k_aggd(const int4* __restrict__ edges0, const int* __restrict__ cur0,
            const int* __restrict__ deg0, const float* __restrict__ dis0,
            const unsigned short* __restrict__ X0, unsigned short* __restrict__ acat0,
            const int4* __restrict__ edges1, const int* __restrict__ cur1,
            const int* __restrict__ deg1, const float* __restrict__ dis1,
            const unsigned short* __restrict__ X1, unsigned short* __restrict__ acat1) {
    int b = blockIdx.x;
    int lvl = b >= AGGB;
    const int4* edges = lvl ? edges1 : edges0;
    const int* cur = lvl ? cur1 : cur0;
    const int* deg = lvl ? deg1 : deg0;
    const float* dis = lvl ? dis1 : dis0;
    const unsigned short* X = lvl ? X1 : X0;
    unsigned short* acat = lvl ? acat1 : acat0;
    int wave = ((b - (lvl ? AGGB : 0)) * 256 + threadIdx.x) >> 6;
    int lane = threadIdx.x & 63;
    if (wave >= NN) return;
    int end = cur[wave];
    int start = end - deg[wave];
    float dn = dis[wave];
    int c0 = lane * 2;
    float a1l0 = 0.f, a1h0 = 0.f, a2l0 = 0.f, a2h0 = 0.f;
    float a1l1 = 0.f, a1h1 = 0.f, a2l1 = 0.f, a2h1 = 0.f;
    int s = start;
    for (; s + 8 <= end; s += 8) {
        AEDGE(0) AEDGE(1) AEDGE(2) AEDGE(3) AEDGE(4) AEDGE(5) AEDGE(6) AEDGE(7)
        AACC(0, a1l0, a1h0, a2l0, a2h0); AACC(1, a1l1, a1h1, a2l1, a2h1);
        AACC(2, a1l0, a1h0, a2l0, a2h0); AACC(3, a1l1, a1h1, a2l1, a2h1);
        AACC(4, a1l0, a1h0, a2l0, a2h0); AACC(5, a1l1, a1h1, a2l1, a2h1);
        AACC(6, a1l0, a1h0, a2l0, a2h0); AACC(7, a1l1, a1h1, a2l1, a2h1);
    }
    for (; s < end; s++) {
        AEDGE(0)
        AACC(0, a1l0, a1h0, a2l0, a2h0);
    }
    // analytic self loop
    {
        unsigned int q = *(const unsigned int*)(X + wave * DD + c0);
        float xl = bits_to_f(q << 16), xh = bits_to_f(q & 0xFFFF0000u);
        float dn2 = dn * dn;
        a1l0 = fmaf(dn2, xl, a1l0); a1h0 = fmaf(dn2, xh, a1h0);
        a2l0 += xl; a2h0 += xh;
    }
    float s1l = a1l0 + a1l1, s1h = a1h0 + a1h1;
    float s2l = a2l0 + a2l1, s2h = a2h0 + a2h1;
    unsigned int pk1 = (unsigned int)f_to_bfbits(s1l) |
                       ((unsigned int)f_to_bfbits(s1h) << 16);
    unsigned int pk2 = (unsigned int)f_to_bfbits(s2l) |
                       ((unsigned int)f_to_bfbits(s2h) << 16);
    *(unsigned int*)(acat + wave * 256 + c0) = pk1;
    *(unsigned int*)(acat + wave * 256 + 128 + c0) = pk2;
}

// ---------------- Launch ----------------

#define PADUP(x) (((x) + 255) & ~(size_t)255)

extern "C" void kernel_launch(void* const* d_in, const int* in_sizes, int n_in,
                              void* d_out, int out_size, void* d_ws, size_t ws_size,
                              hipStream_t stream) {
    (void)in_sizes; (void)n_in; (void)out_size; (void)ws_size;

    const void* x    = d_in[0];
    const void* d2an = d_in[1];
    const int*  ei0  = (const int*)d_in[2];
    const void* ea0  = d_in[3];
    const int*  ei1  = (const int*)d_in[4];
    const void* ea1  = d_in[5];

    char* p = (char*)d_ws;
    unsigned short* xpe1 = (unsigned short*)p; p += PADUP((size_t)NN * DD * 2);
    unsigned short* xpe2 = (unsigned short*)p; p += PADUP((size_t)NN * DD * 2);
    unsigned short* x0b  = (unsigned short*)p; p += PADUP((size_t)NN * DD * 2);
    unsigned short* xm   = (unsigned short*)p; p += PADUP((size_t)NN * DD * 2);
    unsigned short* xcat = (unsigned short*)p; p += PADUP((size_t)NN * 256 * 2);
    unsigned short* acat0 = xcat;              // xcat dead after PE GEMM
    unsigned short* acat1 = (unsigned short*)p; p += PADUP((size_t)NN * 256 * 2);
    unsigned short* wt   = (unsigned short*)p; p += PADUP((size_t)6 * WSLOT * 2);
    int*   deg0 = (int*)p;    p += PADUP((size_t)NN * 4);
    int*   cur0 = (int*)p;    p += PADUP((size_t)NN * 4);
    float* dis0 = (float*)p;  p += PADUP((size_t)NN * 4);
    int*   deg1 = (int*)p;    p += PADUP((size_t)NN * 4);
    int*   cur1 = (int*)p;    p += PADUP((size_t)NN * 4);
    float* dis1 = (float*)p;  p += PADUP((size_t)NN * 4);
    int4*  edges0 = (int4*)p; p += PADUP((size_t)NE * 16);
    int4*  edges1 = (int4*)p; p += PADUP((size_t)NE * 16);
    int*   bsum = (int*)p;    p += PADUP((size_t)128 * 4);
    int*   boff = (int*)p;    p += PADUP((size_t)128 * 4);
    int*   dflag = (int*)p;

    // 1. detect + zero degrees
    k_detect0<<<392, 256, 0, stream>>>((const unsigned int*)x, dflag, (float*)d_out,
                                       deg0, deg1);
    // 2. hist + prepx + weight prep (homogeneous-ish streaming, fused)
    kA<<<2 * HISTB + PREPXB + PREPB, 256, 0, stream>>>(
        ei0, ei1, deg0, deg1, x, d2an, xcat,
        d_in[6], d_in[7], d_in[8], d_in[9], d_in[10], d_in[11], d_in[12],
        d_in[13], d_in[14], d_in[15], wt, dflag);
    // 3-5. parallel scan
    k_scan1<<<dim3(NB, 2), 256, 0, stream>>>(deg0, deg1, dis0, dis1, bsum, NN);
    k_scan2<<<1, 128, 0, stream>>>(bsum, boff);
    k_scan3<<<dim3(NB, 2), 256, 0, stream>>>(deg0, deg1, boff, cur0, cur1, NN);
    // 6. edge fill (separate — needs full occupancy for scatter latency)
    k_fill<<<dim3(FILLB, 2), 256, 0, stream>>>(ei0, ea0, dis0, cur0, edges0,
                                               ei1, ea1, dis1, cur1, edges1, dflag);
    // 7. PE GEMM: xpe1/xpe2 = xcat @ nodeLin{1,2}   (last reader of xcat)
    k_gemm_pe<<<dim3(GX, 2), 256, 0, stream>>>(xcat, wt, xpe1, xpe2);
    // 8. dual agg round 1: acat0 = agg0(xpe1), acat1 = agg1(xpe2)
    k_aggd<<<2 * AGGB, 256, 0, stream>>>(edges0, cur0, deg0, dis0, xpe1, acat0,
                                         edges1, cur1, deg1, dis1, xpe2, acat1);
    // 9. x0 = relu(acat0 @ Wcat_1) -> x0b
    k_gemmL<<<GX, 256, 0, stream>>>(acat0, wt + 2 * WSLOT,
                                    (const unsigned short*)0, x0b, (void*)0,
                                    dflag, 1);
    // 10. xm = 0.5*relu(acat1 @ Wcat_2) + 0.5*x0b
    k_gemmL<<<GX, 256, 0, stream>>>(acat1, wt + 3 * WSLOT, x0b, xm, (void*)0,
                                    dflag, 2);
    // 11. dual agg round 2: acat0 = agg0(xm), acat1 = agg1(xm)
    k_aggd<<<2 * AGGB, 256, 0, stream>>>(edges0, cur0, deg0, dis0, xm, acat0,
                                         edges1, cur1, deg1, dis1, xm, acat1);
    // 12. x0 = relu(acat0 @ Wcat_3) -> x0b
    k_gemmL<<<GX, 256, 0, stream>>>(acat0, wt + 4 * WSLOT,
                                    (const unsigned short*)0, x0b, (void*)0,
                                    dflag, 1);
    // 13. out = 0.5*relu(acat1 @ Wcat_4) + 0.5*x0b  (bf16/f32 per dflag)
    k_gemmL<<<GX, 256, 0, stream>>>(acat1, wt + 5 * WSLOT, x0b,
                                    (unsigned short*)0, d_out, dflag, 3);
}